// Round 1
// baseline (348.184 us; speedup 1.0000x reference)
//
#include <hip/hip_runtime.h>
#include <math.h>

#define PI_F 3.14159265358979323846f

// ---------------- Kernel A: layers 1-2 (width 16) ----------------
__global__ __launch_bounds__(256) void kA(
    const float* __restrict__ ch,
    const float* __restrict__ wl1, const float* __restrict__ bl1,
    const float* __restrict__ wg1, const float* __restrict__ bg1,
    const float* __restrict__ wl2, const float* __restrict__ bl2,
    const float* __restrict__ wg2, const float* __restrict__ bg2,
    float* __restrict__ f2out)
{
    __shared__ float xls[10*16];
    __shared__ float f1[64*16];
    __shared__ float gt[32*16];
    int b = blockIdx.x, tid = threadIdx.x;
    if (tid < 160) xls[tid] = ch[b*160 + tid];
    __syncthreads();
    #pragma unroll
    for (int it = 0; it < 4; ++it) {
        int t = tid + it*256; int o = t >> 4, n = t & 15;
        int isg = o >= 32; int oo = o & 31;
        const float* w = isg ? wg1 : wl1;
        float acc = (isg ? bg1 : bl1)[oo];
        #pragma unroll
        for (int c = 0; c < 10; ++c) acc = fmaf(w[oo*10+c], xls[c*16+n], acc);
        acc = fmaxf(acc, 0.f);
        if (isg) gt[oo*16+n] = acc; else f1[o*16+n] = acc;
    }
    __syncthreads();
    if (tid < 32) {
        float s = 0.f;
        #pragma unroll
        for (int n = 0; n < 16; ++n) s += gt[tid*16+n];
        s *= (1.f/16.f);
        #pragma unroll
        for (int n = 0; n < 16; ++n) f1[(32+tid)*16+n] = s;
    }
    __syncthreads();
    #pragma unroll
    for (int it = 0; it < 4; ++it) {
        int t = tid + it*256; int o = t >> 4, n = t & 15;
        int isg = o >= 32; int oo = o & 31;
        const float* w = isg ? wg2 : wl2;
        float acc = (isg ? bg2 : bl2)[oo];
        #pragma unroll
        for (int c = 0; c < 64; ++c) acc = fmaf(w[oo*64+c], f1[c*16+n], acc);
        acc = fmaxf(acc, 0.f);
        if (isg) gt[oo*16+n] = acc; else f2out[b*1024 + o*16 + n] = acc;
    }
    __syncthreads();
    if (tid < 32) {
        float s = 0.f;
        #pragma unroll
        for (int n = 0; n < 16; ++n) s += gt[tid*16+n];
        s *= (1.f/16.f);
        #pragma unroll
        for (int n = 0; n < 16; ++n) f2out[b*1024 + (32+tid)*16 + n] = s;
    }
}

// ---------------- Kernel B: layers 3-5 (width 144) ----------------
__global__ __launch_bounds__(256) void kB(
    const float* __restrict__ f2in,
    const float* __restrict__ wl3, const float* __restrict__ bl3,
    const float* __restrict__ wg3, const float* __restrict__ bg3,
    const float* __restrict__ wl4, const float* __restrict__ bl4,
    const float* __restrict__ wg4, const float* __restrict__ bg4,
    const float* __restrict__ wl5, const float* __restrict__ bl5,
    const float* __restrict__ wg5, const float* __restrict__ bg5,
    const int* __restrict__ perm3,
    float* __restrict__ x5locg, float* __restrict__ x5meang)
{
    __shared__ float f2l[64*16];       // input
    __shared__ float cat3[7*32*16];    // layer3 local, natural (f,o,n)
    __shared__ float g3m[7*33];        // layer3 global means (padded)
    __shared__ float x3s[32*144];      // layer3 output local rows
    __shared__ float x4s[32*144];      // layer4 output local rows
    __shared__ float x4m[32];          // layer4 output mean rows
    __shared__ float gtm[32*145];      // global-path relu values (padded)
    __shared__ float gmp[32*4];
    __shared__ int   pf3[144], pn3[144];
    int b = blockIdx.x, tid = threadIdx.x;

    ((float4*)f2l)[tid] = ((const float4*)(f2in + b*1024))[tid];
    if (tid < 144) { int p = perm3[tid]; pf3[tid] = p >> 4; pn3[tid] = p & 15; }
    __syncthreads();

    // layer3 local (only f<7 ever used)
    for (int t = tid; t < 3584; t += 256) {
        int f = t >> 9, o = (t >> 4) & 31, n = t & 15;
        float acc = bl3[f*32+o];
        const float* w = wl3 + (f*32+o)*64;
        #pragma unroll
        for (int c = 0; c < 64; ++c) acc = fmaf(w[c], f2l[c*16+n], acc);
        cat3[(f*32+o)*16+n] = fmaxf(acc, 0.f);
    }
    // layer3 global means (f<7)
    if (tid < 224) {
        int f = tid >> 5, j = tid & 31;
        const float* w = wg3 + (f*32+j)*64;
        float bb = bg3[f*32+j];
        float s = 0.f;
        for (int n = 0; n < 16; ++n) {
            float acc = bb;
            #pragma unroll
            for (int c = 0; c < 64; ++c) acc = fmaf(w[c], f2l[c*16+n], acc);
            s += fmaxf(acc, 0.f);
        }
        g3m[f*33+j] = s * (1.f/16.f);
    }
    __syncthreads();
    // gather into x3 local rows
    for (int t = tid; t < 4608; t += 256) {
        int o = t / 144, w = t - o*144;
        x3s[o*144+w] = cat3[(pf3[w]*32+o)*16 + pn3[w]];
    }
    __syncthreads();

    // ---- layer 4: 2o x 4w tiles; tasks 0..575 local, 576..1151 global
    for (int t = tid; t < 1152; t += 256) {
        int isg = (t >= 576);
        int tt = isg ? (t - 576) : t;
        int op = tt / 36, wq = tt - op*36;
        int o0 = op*2, w0 = wq*4;
        const float* wmat = isg ? wg4 : wl4;
        const float* bv   = isg ? bg4 : bl4;
        const float* wr0 = wmat + o0*64;
        const float* wr1 = wmat + (o0+1)*64;
        float acc[2][4];
        {
            float b0 = bv[o0], b1 = bv[o0+1];
            #pragma unroll
            for (int q = 0; q < 4; ++q) { acc[0][q] = b0; acc[1][q] = b1; }
        }
        #pragma unroll
        for (int c = 0; c < 32; ++c) {
            float4 xv = *(const float4*)&x3s[c*144 + w0];
            float wa = wr0[c], wb = wr1[c];
            acc[0][0] = fmaf(wa, xv.x, acc[0][0]);
            acc[0][1] = fmaf(wa, xv.y, acc[0][1]);
            acc[0][2] = fmaf(wa, xv.z, acc[0][2]);
            acc[0][3] = fmaf(wa, xv.w, acc[0][3]);
            acc[1][0] = fmaf(wb, xv.x, acc[1][0]);
            acc[1][1] = fmaf(wb, xv.y, acc[1][1]);
            acc[1][2] = fmaf(wb, xv.z, acc[1][2]);
            acc[1][3] = fmaf(wb, xv.w, acc[1][3]);
        }
        int fq0 = pf3[w0], fq1 = pf3[w0+1], fq2 = pf3[w0+2], fq3 = pf3[w0+3];
        #pragma unroll
        for (int c = 0; c < 32; ++c) {
            float wa = wr0[32+c], wb = wr1[32+c];
            float g0 = g3m[fq0*33+c], g1 = g3m[fq1*33+c];
            float g2 = g3m[fq2*33+c], g3v = g3m[fq3*33+c];
            acc[0][0] = fmaf(wa, g0, acc[0][0]);
            acc[0][1] = fmaf(wa, g1, acc[0][1]);
            acc[0][2] = fmaf(wa, g2, acc[0][2]);
            acc[0][3] = fmaf(wa, g3v, acc[0][3]);
            acc[1][0] = fmaf(wb, g0, acc[1][0]);
            acc[1][1] = fmaf(wb, g1, acc[1][1]);
            acc[1][2] = fmaf(wb, g2, acc[1][2]);
            acc[1][3] = fmaf(wb, g3v, acc[1][3]);
        }
        #pragma unroll
        for (int i = 0; i < 2; ++i)
            #pragma unroll
            for (int q = 0; q < 4; ++q) {
                float v = fmaxf(acc[i][q], 0.f);
                if (isg) gtm[(o0+i)*145 + w0+q] = v;
                else     x4s[(o0+i)*144 + w0+q] = v;
            }
    }
    __syncthreads();
    if (tid < 128) {
        int j = tid >> 2, q = tid & 3;
        float s = 0.f;
        for (int n = q*36; n < q*36+36; ++n) s += gtm[j*145+n];
        gmp[j*4+q] = s;
    }
    __syncthreads();
    if (tid < 32) x4m[tid] = (gmp[tid*4]+gmp[tid*4+1]+gmp[tid*4+2]+gmp[tid*4+3]) * (1.f/144.f);
    __syncthreads();

    // ---- layer 5: same tiling; local rows -> global ws, g-path -> gtm
    for (int t = tid; t < 1152; t += 256) {
        int isg = (t >= 576);
        int tt = isg ? (t - 576) : t;
        int op = tt / 36, wq = tt - op*36;
        int o0 = op*2, w0 = wq*4;
        const float* wmat = isg ? wg5 : wl5;
        const float* bv   = isg ? bg5 : bl5;
        const float* wr0 = wmat + o0*64;
        const float* wr1 = wmat + (o0+1)*64;
        float p0s = 0.f, p1s = 0.f;
        #pragma unroll
        for (int c = 0; c < 32; ++c) {
            p0s = fmaf(wr0[32+c], x4m[c], p0s);
            p1s = fmaf(wr1[32+c], x4m[c], p1s);
        }
        float acc[2][4];
        {
            float b0 = bv[o0] + p0s, b1 = bv[o0+1] + p1s;
            #pragma unroll
            for (int q = 0; q < 4; ++q) { acc[0][q] = b0; acc[1][q] = b1; }
        }
        #pragma unroll
        for (int c = 0; c < 32; ++c) {
            float4 xv = *(const float4*)&x4s[c*144 + w0];
            float wa = wr0[c], wb = wr1[c];
            acc[0][0] = fmaf(wa, xv.x, acc[0][0]);
            acc[0][1] = fmaf(wa, xv.y, acc[0][1]);
            acc[0][2] = fmaf(wa, xv.z, acc[0][2]);
            acc[0][3] = fmaf(wa, xv.w, acc[0][3]);
            acc[1][0] = fmaf(wb, xv.x, acc[1][0]);
            acc[1][1] = fmaf(wb, xv.y, acc[1][1]);
            acc[1][2] = fmaf(wb, xv.z, acc[1][2]);
            acc[1][3] = fmaf(wb, xv.w, acc[1][3]);
        }
        #pragma unroll
        for (int i = 0; i < 2; ++i)
            #pragma unroll
            for (int q = 0; q < 4; ++q) {
                float v = fmaxf(acc[i][q], 0.f);
                if (isg) gtm[(o0+i)*145 + w0+q] = v;
                else     x5locg[b*4608 + (o0+i)*144 + w0+q] = v;
            }
    }
    __syncthreads();
    if (tid < 128) {
        int j = tid >> 2, q = tid & 3;
        float s = 0.f;
        for (int n = q*36; n < q*36+36; ++n) s += gtm[j*145+n];
        gmp[j*4+q] = s;
    }
    __syncthreads();
    if (tid < 32) x5meang[b*32+tid] = (gmp[tid*4]+gmp[tid*4+1]+gmp[tid*4+2]+gmp[tid*4+3]) * (1.f/144.f);
}

// ---------------- Kernel C: layers 6-8 (width 1296) ----------------
__global__ __launch_bounds__(512) void kC(
    const float* __restrict__ x5locg, const float* __restrict__ x5meang,
    const float* __restrict__ wl6, const float* __restrict__ bl6,
    const float* __restrict__ wg6, const float* __restrict__ bg6,
    const float* __restrict__ wl7, const float* __restrict__ bl7,
    const float* __restrict__ wg7, const float* __restrict__ bg7,
    const float* __restrict__ wl8, const float* __restrict__ bl8,
    const int* __restrict__ perm6,
    float* __restrict__ out)
{
    __shared__ float x5T[144*68];   // row n: cols 0-31 local, 32-63 mean
    __shared__ float W6[7*32*64];
    __shared__ float W7[64*64];     // rows 0-31 wl7, 32-63 wg7
    __shared__ float bl6s[7*32];
    __shared__ float b7s[64];
    __shared__ float wl8s[64];
    __shared__ float g6m[7*32];
    __shared__ float x5ms[32];
    __shared__ int   pml[1296];
    __shared__ int   cnt[1008];
    __shared__ float l8v[1008];
    __shared__ float redbuf[8];
    __shared__ float CbS;
    int b = blockIdx.x, tid = threadIdx.x;

    // ---- stage
    for (int t = tid; t < 3584; t += 512) ((float4*)W6)[t] = ((const float4*)wl6)[t];
    ((float4*)W7)[tid & 511] = ((const float4*)wl7)[tid & 511];
    ((float4*)(W7+2048))[tid & 511] = ((const float4*)wg7)[tid & 511];
    if (tid < 224) { bl6s[tid] = bl6[tid]; g6m[tid] = 0.f; }
    if (tid < 32) { b7s[tid] = bl7[tid]; b7s[32+tid] = bg7[tid]; x5ms[tid] = x5meang[b*32+tid]; }
    if (tid < 64) wl8s[tid] = wl8[tid];
    for (int t = tid; t < 1008; t += 512) cnt[t] = 0;
    __syncthreads();
    for (int t = tid; t < 1296; t += 512) {
        int p = perm6[t]; pml[t] = p;
        atomicAdd(&cnt[p], 1);
    }
    for (int t = tid; t < 1152; t += 512) {
        float4 v = ((const float4*)(x5locg + b*4608))[t];
        int o = t / 36, w = (t - o*36)*4;
        x5T[(w+0)*68 + o] = v.x;
        x5T[(w+1)*68 + o] = v.y;
        x5T[(w+2)*68 + o] = v.z;
        x5T[(w+3)*68 + o] = v.w;
    }
    __syncthreads();
    for (int t = tid; t < 4608; t += 512) {
        int n = t >> 5, j = t & 31;
        x5T[n*68 + 32 + j] = x5ms[j];
    }
    __syncthreads();

    // ---- g6 means (f<7): mean over n of relu(wg6[f] @ x5col + bg6)
    for (int t = tid; t < 896; t += 512) {
        int f = t >> 7, j = (t >> 2) & 31, q = t & 3;
        const float* wr = wg6 + (f*32+j)*64;
        float wreg[64];
        #pragma unroll
        for (int k4 = 0; k4 < 16; ++k4) {
            float4 wv = ((const float4*)wr)[k4];
            wreg[k4*4] = wv.x; wreg[k4*4+1] = wv.y; wreg[k4*4+2] = wv.z; wreg[k4*4+3] = wv.w;
        }
        float part2 = 0.f;
        #pragma unroll
        for (int j2 = 0; j2 < 32; ++j2) part2 = fmaf(wreg[32+j2], x5ms[j2], part2);
        float bb = bg6[f*32+j] + part2;
        float s = 0.f;
        for (int n = q*36; n < q*36+36; ++n) {
            const float* xr = &x5T[n*68];
            float acc = bb;
            #pragma unroll
            for (int k4 = 0; k4 < 8; ++k4) {
                float4 xv = ((const float4*)xr)[k4];
                acc = fmaf(wreg[k4*4],   xv.x, acc);
                acc = fmaf(wreg[k4*4+1], xv.y, acc);
                acc = fmaf(wreg[k4*4+2], xv.z, acc);
                acc = fmaf(wreg[k4*4+3], xv.w, acc);
            }
            s += fmaxf(acc, 0.f);
        }
        atomicAdd(&g6m[f*32+j], s);
    }
    __syncthreads();
    if (tid < 224) g6m[tid] *= (1.f/144.f);
    __syncthreads();

    // ---- per-column pipeline: l6 local -> l7 (l+g) -> l8 scalars
    float gacc = 0.f;
    if (tid < 504) {
        int p0 = tid*2;
        int f = p0 / 144;
        int n0 = p0 - f*144;
        const float* w6f = W6 + f*2048;
        const float* xr0 = &x5T[n0*68];
        const float* xr1 = &x5T[(n0+1)*68];
        float col0[32], col1[32];
        #pragma unroll
        for (int o = 0; o < 32; ++o) { float bb = bl6s[f*32+o]; col0[o] = bb; col1[o] = bb; }
        for (int k16 = 0; k16 < 4; ++k16) {
            float4 xx0[4], xx1[4];
            #pragma unroll
            for (int i = 0; i < 4; ++i) {
                xx0[i] = ((const float4*)xr0)[k16*4+i];
                xx1[i] = ((const float4*)xr1)[k16*4+i];
            }
            const float* wbase = w6f + k16*16;
            #pragma unroll
            for (int o = 0; o < 32; ++o) {
                const float* wrow = wbase + o*64;
                #pragma unroll
                for (int i = 0; i < 4; ++i) {
                    float4 wv = ((const float4*)wrow)[i];
                    col0[o] = fmaf(wv.x, xx0[i].x, col0[o]);
                    col0[o] = fmaf(wv.y, xx0[i].y, col0[o]);
                    col0[o] = fmaf(wv.z, xx0[i].z, col0[o]);
                    col0[o] = fmaf(wv.w, xx0[i].w, col0[o]);
                    col1[o] = fmaf(wv.x, xx1[i].x, col1[o]);
                    col1[o] = fmaf(wv.y, xx1[i].y, col1[o]);
                    col1[o] = fmaf(wv.z, xx1[i].z, col1[o]);
                    col1[o] = fmaf(wv.w, xx1[i].w, col1[o]);
                }
            }
        }
        #pragma unroll
        for (int o = 0; o < 32; ++o) { col0[o] = fmaxf(col0[o], 0.f); col1[o] = fmaxf(col1[o], 0.f); }
        float g6r[32];
        #pragma unroll
        for (int i = 0; i < 8; ++i) {
            float4 gv = ((const float4*)(g6m + f*32))[i];
            g6r[i*4] = gv.x; g6r[i*4+1] = gv.y; g6r[i*4+2] = gv.z; g6r[i*4+3] = gv.w;
        }
        float c0f = (float)cnt[p0], c1f = (float)cnt[p0+1];
        float l8a0 = 0.f, l8a1 = 0.f;
        for (int o7 = 0; o7 < 64; ++o7) {
            const float* wr = W7 + o7*64;
            float sg = 0.f;
            #pragma unroll
            for (int i = 0; i < 8; ++i) {
                float4 wv = ((const float4*)wr)[8+i];
                sg = fmaf(wv.x, g6r[i*4],   sg);
                sg = fmaf(wv.y, g6r[i*4+1], sg);
                sg = fmaf(wv.z, g6r[i*4+2], sg);
                sg = fmaf(wv.w, g6r[i*4+3], sg);
            }
            float s0 = b7s[o7] + sg, s1 = s0;
            #pragma unroll
            for (int i = 0; i < 8; ++i) {
                float4 wv = ((const float4*)wr)[i];
                s0 = fmaf(wv.x, col0[i*4],   s0);  s1 = fmaf(wv.x, col1[i*4],   s1);
                s0 = fmaf(wv.y, col0[i*4+1], s0);  s1 = fmaf(wv.y, col1[i*4+1], s1);
                s0 = fmaf(wv.z, col0[i*4+2], s0);  s1 = fmaf(wv.z, col1[i*4+2], s1);
                s0 = fmaf(wv.w, col0[i*4+3], s0);  s1 = fmaf(wv.w, col1[i*4+3], s1);
            }
            float v0 = fmaxf(s0, 0.f), v1 = fmaxf(s1, 0.f);
            float wgt = wl8s[o7];
            if (o7 < 32) { l8a0 = fmaf(wgt, v0, l8a0); l8a1 = fmaf(wgt, v1, l8a1); }
            else gacc = fmaf(wgt, fmaf(c0f, v0, c1f*v1), gacc);
        }
        l8v[p0] = l8a0; l8v[p0+1] = l8a1;
    }
    // reduce gacc over block
    #pragma unroll
    for (int off = 32; off > 0; off >>= 1) gacc += __shfl_down(gacc, off);
    int lane = tid & 63, wid = tid >> 6;
    if (lane == 0) redbuf[wid] = gacc;
    __syncthreads();
    if (tid == 0) {
        float s = 0.f;
        #pragma unroll
        for (int i = 0; i < 8; ++i) s += redbuf[i];
        CbS = bl8[0] + s * (1.f/1296.f);
    }
    __syncthreads();
    float Cb = CbS;
    for (int t = tid; t < 1296; t += 512) {
        out[b*1296 + t] = PI_F * (l8v[pml[t]] + Cb);
    }
}

extern "C" void kernel_launch(void* const* d_in, const int* in_sizes, int n_in,
                              void* d_out, int out_size, void* d_ws, size_t ws_size,
                              hipStream_t stream) {
    (void)in_sizes; (void)n_in; (void)out_size; (void)ws_size;
    const float* ch  = (const float*)d_in[0];
    const float* wl1 = (const float*)d_in[1];  const float* bl1v = (const float*)d_in[2];
    const float* wg1 = (const float*)d_in[3];  const float* bg1v = (const float*)d_in[4];
    const float* wl2 = (const float*)d_in[5];  const float* bl2v = (const float*)d_in[6];
    const float* wg2 = (const float*)d_in[7];  const float* bg2v = (const float*)d_in[8];
    const float* wl4 = (const float*)d_in[9];  const float* bl4v = (const float*)d_in[10];
    const float* wg4 = (const float*)d_in[11]; const float* bg4v = (const float*)d_in[12];
    const float* wl5 = (const float*)d_in[13]; const float* bl5v = (const float*)d_in[14];
    const float* wg5 = (const float*)d_in[15]; const float* bg5v = (const float*)d_in[16];
    const float* wl7 = (const float*)d_in[17]; const float* bl7v = (const float*)d_in[18];
    const float* wg7 = (const float*)d_in[19]; const float* bg7v = (const float*)d_in[20];
    const float* wl3 = (const float*)d_in[21]; const float* bl3v = (const float*)d_in[22];
    const float* wg3 = (const float*)d_in[23]; const float* bg3v = (const float*)d_in[24];
    const float* wl6 = (const float*)d_in[25]; const float* bl6v = (const float*)d_in[26];
    const float* wg6 = (const float*)d_in[27]; const float* bg6v = (const float*)d_in[28];
    const float* wl8 = (const float*)d_in[29]; const float* bl8v = (const float*)d_in[30];
    const int* perm3 = (const int*)d_in[31];
    const int* perm6 = (const int*)d_in[32];
    float* out = (float*)d_out;
    float* ws = (float*)d_ws;
    float* f2     = ws;                      // 512*64*16
    float* x5loc  = ws + 512*1024;           // 512*32*144
    float* x5mean = x5loc + 512*32*144;      // 512*32

    kA<<<512, 256, 0, stream>>>(ch, wl1, bl1v, wg1, bg1v, wl2, bl2v, wg2, bg2v, f2);
    kB<<<512, 256, 0, stream>>>(f2, wl3, bl3v, wg3, bg3v, wl4, bl4v, wg4, bg4v,
                                wl5, bl5v, wg5, bg5v, perm3, x5loc, x5mean);
    kC<<<512, 512, 0, stream>>>(x5loc, x5mean, wl6, bl6v, wg6, bg6v,
                                wl7, bl7v, wg7, bg7v, wl8, bl8v, perm6, out);
}